// Round 10
// baseline (194.718 us; speedup 1.0000x reference)
//
#include <hip/hip_runtime.h>
#include <hip/hip_bf16.h>

typedef unsigned short u16;
typedef __bf16 bf16x8 __attribute__((ext_vector_type(8)));
typedef float f32x4 __attribute__((ext_vector_type(4)));

#define S_LEN 2048
#define HID 2048
#define NH 32
#define NKV 8
#define HD 64

// native RTNE f32->bf16 (single v_cvt op; compiler packs pairs)
__device__ inline u16 f2bf(float x) {
    __bf16 h = (__bf16)x;
    return __builtin_bit_cast(u16, h);
}
__device__ inline float bf2f(u16 u) {
    return __uint_as_float(((unsigned int)u) << 16);
}

__device__ inline void gload_lds16(const u16* g, u16* l) {
    __builtin_amdgcn_global_load_lds((const __attribute__((address_space(1))) unsigned int*)g,
                                     (__attribute__((address_space(3))) unsigned int*)l, 16, 0, 0);
}

// ---------------- fp32 -> bf16 convert, all 5 tensors in one launch ----------------
__global__ void cvt_all(const float* __restrict__ h, const float* __restrict__ wq,
                        const float* __restrict__ wk, const float* __restrict__ wv,
                        const float* __restrict__ wo,
                        u16* __restrict__ hb, u16* __restrict__ wqkv, u16* __restrict__ wob) {
    int i = blockIdx.x * blockDim.x + threadIdx.x;   // float4 index, total 3670016
    const float* src; u16* dst; int o;
    if (i < 1048576)      { src = h;  dst = hb;   o = i; }
    else if (i < 2097152) { src = wq; dst = wqkv; o = i - 1048576; }
    else if (i < 2359296) { src = wk; dst = wqkv + (size_t)2048 * 2048; o = i - 2097152; }
    else if (i < 2621440) { src = wv; dst = wqkv + (size_t)2560 * 2048; o = i - 2359296; }
    else                  { src = wo; dst = wob;  o = i - 2621440; }
    float4 v = ((const float4*)src)[o];
    ushort4 u;
    u.x = f2bf(v.x); u.y = f2bf(v.y); u.z = f2bf(v.z); u.w = f2bf(v.w);
    ((ushort4*)dst)[o] = u;
}

// ---------------- GEMM: C[M,N] = A[M,K] * B[N,K]^T (both bf16 row-major) ----------------
// 64x128 tile, 4 waves as 2x2 (wave = 32 rows x 64 cols), BK=32, double-buffered.
// mode 1: store fp32 row-major (ldc)
// mode 3: fused QKV epilogue with RoPE (wave col-span = 64 = one head)
__global__ __launch_bounds__(256) void gemm_bt(const u16* __restrict__ A,
                                               const u16* __restrict__ B,
                                               void* __restrict__ Cv,
                                               int K_, int mode, int ldc,
                                               const float* __restrict__ cosp,
                                               const float* __restrict__ sinp) {
    __shared__ u16 As[2][64 * 32];
    __shared__ u16 Bs[2][128 * 32];
    const int t = threadIdx.x;
    // XCD-aware bijective swizzle (nwg % 8 == 0 for both call sites)
    const int nwg = gridDim.x * gridDim.y;
    const int orig = blockIdx.y * gridDim.x + blockIdx.x;
    const int wgid = (orig & 7) * (nwg >> 3) + (orig >> 3);
    const int bm = wgid % gridDim.x, bn = wgid / gridDim.x;
    const int lane = t & 63, w = t >> 6;
    const int wr2 = (w >> 1) * 32, wc2 = (w & 1) * 64;
    const int g = lane >> 4, r16 = lane & 15;
    f32x4 acc[2][4] = {};

    // staging: A 64x32 (1 instr/wave: 16 rows), B 128x32 (2 instrs/wave: 32 rows)
    const int srowA = w * 16 + (lane >> 2);
    const int srowB = w * 32 + (lane >> 2);
    const int scol = (lane & 3) * 8;
    const u16* Ap = A + (size_t)(bm * 64 + srowA) * K_ + scol;
    const u16* Bp = B + (size_t)(bn * 128 + srowB) * K_ + scol;
    const int aoff = w * 512;    // 16 rows * 32
    const int boff = w * 1024;   // 32 rows * 32

    // prologue: stage tile 0 into buffer 0
    gload_lds16(Ap, &As[0][aoff]);
    gload_lds16(Bp, &Bs[0][boff]);
    gload_lds16(Bp + (size_t)16 * K_, &Bs[0][boff + 512]);
    __syncthreads();

    int cur = 0;
    for (int kt = 0; kt < K_; kt += 32) {
        const int nxt = kt + 32;
        if (nxt < K_) {   // prefetch next K-step into the other buffer
            gload_lds16(Ap + nxt, &As[cur ^ 1][aoff]);
            gload_lds16(Bp + nxt, &Bs[cur ^ 1][boff]);
            gload_lds16(Bp + nxt + (size_t)16 * K_, &Bs[cur ^ 1][boff + 512]);
        }
        bf16x8 af[2], bfr[4];
#pragma unroll
        for (int i = 0; i < 2; i++) af[i] = *(const bf16x8*)(&As[cur][(wr2 + i * 16 + r16) * 32 + g * 8]);
#pragma unroll
        for (int j = 0; j < 4; j++) bfr[j] = *(const bf16x8*)(&Bs[cur][(wc2 + j * 16 + r16) * 32 + g * 8]);
#pragma unroll
        for (int i = 0; i < 2; i++)
#pragma unroll
            for (int j = 0; j < 4; j++)
                acc[i][j] = __builtin_amdgcn_mfma_f32_16x16x32_bf16(af[i], bfr[j], acc[i][j], 0, 0, 0);
        __syncthreads();   // next-tile stage complete + all waves done reading cur
        cur ^= 1;
    }

    u16* qb_ = (u16*)Cv;
    u16* kb_ = qb_ + (size_t)2048 * 2048;
    u16* vt_ = kb_ + (size_t)512 * 2048;
    if (mode == 1) {
#pragma unroll
        for (int i = 0; i < 2; i++)
#pragma unroll
            for (int j = 0; j < 4; j++)
#pragma unroll
                for (int r = 0; r < 4; r++) {
                    int row = bm * 64 + wr2 + i * 16 + g * 4 + r;
                    int col = bn * 128 + wc2 + j * 16 + r16;
                    ((float*)Cv)[(size_t)row * ldc + col] = acc[i][j][r];
                }
    } else {
        const int cbase = bn * 128 + wc2;   // 64-aligned => wave span = one head
        if (cbase < 2560) {
            // q or k region: fused RoPE on fp32 accumulators (exact pre-round)
            const float scl = (cbase < 2048) ? 0.125f * 1.44269504f : 1.0f;
#pragma unroll
            for (int i = 0; i < 2; i++)
#pragma unroll
                for (int r = 0; r < 4; r++) {
                    int row = bm * 64 + wr2 + i * 16 + g * 4 + r;
#pragma unroll
                    for (int j = 0; j < 2; j++) {
                        int c0 = cbase + j * 16 + r16;
                        int iin = c0 & 63;                 // in-head dim, < 32
                        float x1 = acc[i][j][r], x2 = acc[i][j + 2][r];
                        float cA = cosp[row * 64 + iin],      sA = sinp[row * 64 + iin];
                        float cB = cosp[row * 64 + iin + 32], sB = sinp[row * 64 + iin + 32];
                        u16 o1 = f2bf((x1 * cA - x2 * sA) * scl);
                        u16 o2 = f2bf((x2 * cB + x1 * sB) * scl);
                        if (cbase < 2048) {
                            qb_[(size_t)row * 2048 + c0] = o1;
                            qb_[(size_t)row * 2048 + c0 + 32] = o2;
                        } else {
                            kb_[(size_t)row * 512 + (c0 - 2048)] = o1;
                            kb_[(size_t)row * 512 + (c0 - 2048 + 32)] = o2;
                        }
                    }
                }
        } else {
#pragma unroll
            for (int i = 0; i < 2; i++)
#pragma unroll
                for (int j = 0; j < 4; j++)
#pragma unroll
                    for (int r = 0; r < 4; r++) {
                        int row = bm * 64 + wr2 + i * 16 + g * 4 + r;
                        int col = cbase + j * 16 + r16;
                        vt_[(size_t)(col - 2560) * 2048 + row] = f2bf(acc[i][j][r]);
                    }
        }
    }
}

// ---------------- Flash attention (causal, GQA), folded triangle ----------------
// 1 wave/block. Fragment A = 16 q-rows at j*16, fragment B = 16 q-rows at
// (127-j)*16 -> per-wave work is uniform (16-17 KV tiles). Shared K/V loads.
__global__ __launch_bounds__(64) void attn_kernel(const u16* __restrict__ q,
                                                  const u16* __restrict__ k,
                                                  const u16* __restrict__ vT,
                                                  u16* __restrict__ attn) {
    __shared__ u16 P[2][16][136];  // [frag][qrow][kcol]
    const int bid = blockIdx.x;
    const int h = bid & 31;
    const int j = bid >> 5;             // 0..63 pair index
    const int lane = threadIdx.x & 63;
    const int g = lane >> 4, r16 = lane & 15;
    const int kvh = h >> 2;
    const int qr0[2] = { j * 16, (127 - j) * 16 };
    const int last0 = (qr0[0] >> 7) << 7;   // frag A's last KV tile
    const int last1 = (qr0[1] >> 7) << 7;   // frag B's last KV tile (>= last0)

    bf16x8 qf[2][2];
#pragma unroll
    for (int fi = 0; fi < 2; fi++)
#pragma unroll
        for (int d = 0; d < 2; d++)
            qf[fi][d] = *(const bf16x8*)(q + (size_t)(qr0[fi] + r16) * (NH * HD) + h * HD + d * 32 + g * 8);

    bf16x8 vone;
#pragma unroll
    for (int jj = 0; jj < 8; jj++) vone[jj] = (__bf16)1.0f;

    float m_run[2][4];
    f32x4 o[2][4] = {};
    f32x4 ol[2] = {};   // l ridden as an MFMA ones-column
#pragma unroll
    for (int fi = 0; fi < 2; fi++)
#pragma unroll
        for (int r = 0; r < 4; r++) m_run[fi][r] = -1e30f;

    // prologue: load K tile 0
    bf16x8 kA[4][2], kB[4][2];
#pragma unroll
    for (int s4 = 0; s4 < 4; s4++)
#pragma unroll
        for (int d = 0; d < 2; d++) {
            kA[s4][d] = *(const bf16x8*)(k + (size_t)(s4 * 16 + r16) * (NKV * HD) + kvh * HD + d * 32 + g * 8);
            kB[s4][d] = *(const bf16x8*)(k + (size_t)(64 + s4 * 16 + r16) * (NKV * HD) + kvh * HD + d * 32 + g * 8);
        }

    for (int kv = 0; kv <= last1; kv += 128) {
        const bool actA = (kv <= last0);    // frag A still active (wave-uniform)
        f32x4 sacc[2][8] = {};
        // ---- QK^T on registered K tile ----
#pragma unroll
        for (int s4 = 0; s4 < 4; s4++)
#pragma unroll
            for (int fi = 0; fi < 2; fi++) {
                if (fi == 0 && !actA) continue;
#pragma unroll
                for (int d = 0; d < 2; d++) {
                    sacc[fi][s4] = __builtin_amdgcn_mfma_f32_16x16x32_bf16(qf[fi][d], kA[s4][d], sacc[fi][s4], 0, 0, 0);
                    sacc[fi][4 + s4] = __builtin_amdgcn_mfma_f32_16x16x32_bf16(qf[fi][d], kB[s4][d], sacc[fi][4 + s4], 0, 0, 0);
                }
            }
        // ---- prefetch next K tile (latency hides under softmax+PV) ----
        if (kv + 128 <= last1) {
            const int nk = kv + 128;
#pragma unroll
            for (int s4 = 0; s4 < 4; s4++)
#pragma unroll
                for (int d = 0; d < 2; d++) {
                    kA[s4][d] = *(const bf16x8*)(k + (size_t)(nk + s4 * 16 + r16) * (NKV * HD) + kvh * HD + d * 32 + g * 8);
                    kB[s4][d] = *(const bf16x8*)(k + (size_t)(nk + 64 + s4 * 16 + r16) * (NKV * HD) + kvh * HD + d * 32 + g * 8);
                }
        }
        // ---- V loads issued early: latency hides under softmax ----
        bf16x8 vf[4][4];
#pragma unroll
        for (int kq = 0; kq < 4; kq++)
#pragma unroll
            for (int dblk = 0; dblk < 4; dblk++)
                vf[kq][dblk] = *(const bf16x8*)(vT + (size_t)(kvh * HD + dblk * 16 + r16) * S_LEN + kv + kq * 32 + g * 8);
        // ---- causal mask (per-fragment diagonal tile) ----
#pragma unroll
        for (int fi = 0; fi < 2; fi++) {
            const int lastF = (fi == 0) ? last0 : last1;
            if ((fi == 0 && !actA) || kv != lastF) continue;
#pragma unroll
            for (int sub = 0; sub < 8; sub++)
#pragma unroll
                for (int r = 0; r < 4; r++) {
                    int col = kv + sub * 16 + r16;
                    int row = qr0[fi] + g * 4 + r;
                    if (col > row) sacc[fi][sub][r] = -1e30f;
                }
        }
        // ---- softmax per fragment (max via shfl; sum via MFMA ones-column) ----
#pragma unroll
        for (int fi = 0; fi < 2; fi++) {
            if (fi == 0 && !actA) continue;
            float mt[4];
#pragma unroll
            for (int r = 0; r < 4; r++) {
                float a = fmaxf(fmaxf(sacc[fi][0][r], sacc[fi][1][r]), fmaxf(sacc[fi][2][r], sacc[fi][3][r]));
                float b = fmaxf(fmaxf(sacc[fi][4][r], sacc[fi][5][r]), fmaxf(sacc[fi][6][r], sacc[fi][7][r]));
                mt[r] = fmaxf(a, b);
            }
#pragma unroll
            for (int r = 0; r < 4; r++) {
                mt[r] = fmaxf(mt[r], __shfl_xor(mt[r], 1));
                mt[r] = fmaxf(mt[r], __shfl_xor(mt[r], 2));
                mt[r] = fmaxf(mt[r], __shfl_xor(mt[r], 4));
                mt[r] = fmaxf(mt[r], __shfl_xor(mt[r], 8));
            }
            // defer-max: skip rescale when running max doesn't grow (exact, deterministic)
            bool grow = (mt[0] > m_run[fi][0]) | (mt[1] > m_run[fi][1]) |
                        (mt[2] > m_run[fi][2]) | (mt[3] > m_run[fi][3]);
            if (__any(grow)) {
#pragma unroll
                for (int r = 0; r < 4; r++) {
                    float mn = fmaxf(m_run[fi][r], mt[r]);
                    float alpha = exp2f(m_run[fi][r] - mn);
                    m_run[fi][r] = mn;
                    ol[fi][r] *= alpha;
#pragma unroll
                    for (int dblk = 0; dblk < 4; dblk++) o[fi][dblk][r] *= alpha;
                }
            }
            // exp2 + P (C-layout) -> LDS with native packed cvt
#pragma unroll
            for (int sub = 0; sub < 8; sub++)
#pragma unroll
                for (int r = 0; r < 4; r++)
                    P[fi][g * 4 + r][sub * 16 + r16] = f2bf(exp2f(sacc[fi][sub][r] - m_run[fi][r]));
        }
        // ---- PV: per active frag, 20 MFMA (4 dblk + 1 ones-column per kq) ----
#pragma unroll
        for (int fi = 0; fi < 2; fi++) {
            if (fi == 0 && !actA) continue;
#pragma unroll
            for (int kq = 0; kq < 4; kq++) {
                bf16x8 pf = *(const bf16x8*)(&P[fi][r16][kq * 32 + g * 8]);
                ol[fi] = __builtin_amdgcn_mfma_f32_16x16x32_bf16(pf, vone, ol[fi], 0, 0, 0);
#pragma unroll
                for (int dblk = 0; dblk < 4; dblk++)
                    o[fi][dblk] = __builtin_amdgcn_mfma_f32_16x16x32_bf16(pf, vf[kq][dblk], o[fi][dblk], 0, 0, 0);
            }
        }
    }
#pragma unroll
    for (int fi = 0; fi < 2; fi++) {
        float inv[4];
#pragma unroll
        for (int r = 0; r < 4; r++) inv[r] = 1.0f / ol[fi][r];
#pragma unroll
        for (int dblk = 0; dblk < 4; dblk++)
#pragma unroll
            for (int r = 0; r < 4; r++) {
                float val = o[fi][dblk][r] * inv[r];
                attn[(size_t)(qr0[fi] + g * 4 + r) * (NH * HD) + h * HD + dblk * 16 + r16] = f2bf(val);
            }
    }
}

extern "C" void kernel_launch(void* const* d_in, const int* in_sizes, int n_in,
                              void* d_out, int out_size, void* d_ws, size_t ws_size,
                              hipStream_t stream) {
    const float* hidden = (const float*)d_in[0];
    const float* Wq = (const float*)d_in[1];
    const float* Wk = (const float*)d_in[2];
    const float* Wv = (const float*)d_in[3];
    const float* Wo = (const float*)d_in[4];
    const float* cosp = (const float*)d_in[5];
    const float* sinp = (const float*)d_in[6];
    float* out = (float*)d_out;

    char* ws = (char*)d_ws;
    u16* hb   = (u16*)(ws);                        // 8 MB  [2048,2048]
    u16* wqkv = (u16*)(ws + ((size_t)8 << 20));    // 12 MB [3072,2048] (Wq;Wk;Wv)
    u16* wob  = (u16*)(ws + ((size_t)20 << 20));   // 8 MB  [2048,2048]
    u16* qbuf = (u16*)(ws + ((size_t)28 << 20));   // 8 MB  [2048,2048]  (kbuf, vT follow contiguously)
    u16* kbuf = qbuf + (size_t)2048 * 2048;        // 2 MB  [2048,512]
    u16* vT   = kbuf + (size_t)512 * 2048;         // 2 MB  [512,2048]
    u16* attn = (u16*)(ws + ((size_t)40 << 20));   // 8 MB  [2048,2048]

    // single fused fp32->bf16 conversion launch
    cvt_all<<<14336, 256, 0, stream>>>(hidden, Wq, Wk, Wv, Wo, hb, wqkv, wob);

    // fused QKV projection + RoPE epilogue: [2048,2048] x [3072,2048]^T, 64x128 tiles
    gemm_bt<<<dim3(32, 24), 256, 0, stream>>>(hb, wqkv, qbuf, HID, 3, 0, cosp, sinp);

    // flash attention: folded-triangle pairing, uniform work per wave
    attn_kernel<<<S_LEN / 32 * NH, 64, 0, stream>>>(qbuf, kbuf, vT, attn);

    // output projection -> fp32, 64x128 tiles
    gemm_bt<<<dim3(32, 16), 256, 0, stream>>>(attn, wob, out, HID, 1, HID, nullptr, nullptr);

    (void)in_sizes; (void)n_in; (void)out_size; (void)ws_size;
}

// Round 11
// 182.459 us; speedup vs baseline: 1.0672x; 1.0672x over previous
//
#include <hip/hip_runtime.h>
#include <hip/hip_bf16.h>

typedef unsigned short u16;
typedef __bf16 bf16x8 __attribute__((ext_vector_type(8)));
typedef float f32x4 __attribute__((ext_vector_type(4)));

#define S_LEN 2048
#define HID 2048
#define NH 32
#define NKV 8
#define HD 64

// native RTNE f32->bf16 (single v_cvt op; compiler packs pairs)
__device__ inline u16 f2bf(float x) {
    __bf16 h = (__bf16)x;
    return __builtin_bit_cast(u16, h);
}
__device__ inline float bf2f(u16 u) {
    return __uint_as_float(((unsigned int)u) << 16);
}

__device__ inline void gload_lds16(const u16* g, u16* l) {
    __builtin_amdgcn_global_load_lds((const __attribute__((address_space(1))) unsigned int*)g,
                                     (__attribute__((address_space(3))) unsigned int*)l, 16, 0, 0);
}

// ---------------- fp32 -> bf16 convert, all 5 tensors in one launch ----------------
__global__ void cvt_all(const float* __restrict__ h, const float* __restrict__ wq,
                        const float* __restrict__ wk, const float* __restrict__ wv,
                        const float* __restrict__ wo,
                        u16* __restrict__ hb, u16* __restrict__ wqkv, u16* __restrict__ wob) {
    int i = blockIdx.x * blockDim.x + threadIdx.x;   // float4 index, total 3670016
    const float* src; u16* dst; int o;
    if (i < 1048576)      { src = h;  dst = hb;   o = i; }
    else if (i < 2097152) { src = wq; dst = wqkv; o = i - 1048576; }
    else if (i < 2359296) { src = wk; dst = wqkv + (size_t)2048 * 2048; o = i - 2097152; }
    else if (i < 2621440) { src = wv; dst = wqkv + (size_t)2560 * 2048; o = i - 2359296; }
    else                  { src = wo; dst = wob;  o = i - 2621440; }
    float4 v = ((const float4*)src)[o];
    ushort4 u;
    u.x = f2bf(v.x); u.y = f2bf(v.y); u.z = f2bf(v.z); u.w = f2bf(v.w);
    ((ushort4*)dst)[o] = u;
}

// ---------------- GEMM: C[M,N] = A[M,K] * B[N,K]^T (both bf16 row-major) ----------------
// 64x128 tile, BK=64 (one barrier per 64-K step), 4 waves as 2x2, double-buffered.
// mode 1: store fp32 row-major (ldc)
// mode 3: fused QKV epilogue with RoPE (wave col-span = 64 = one head)
__global__ __launch_bounds__(256) void gemm_bt(const u16* __restrict__ A,
                                               const u16* __restrict__ B,
                                               void* __restrict__ Cv,
                                               int K_, int mode, int ldc,
                                               const float* __restrict__ cosp,
                                               const float* __restrict__ sinp) {
    __shared__ u16 As[2][64 * 64];    // 16 KB
    __shared__ u16 Bs[2][128 * 64];   // 32 KB
    const int t = threadIdx.x;
    // XCD-aware bijective swizzle (nwg % 8 == 0 for both call sites)
    const int nwg = gridDim.x * gridDim.y;
    const int orig = blockIdx.y * gridDim.x + blockIdx.x;
    const int wgid = (orig & 7) * (nwg >> 3) + (orig >> 3);
    const int bm = wgid % gridDim.x, bn = wgid / gridDim.x;
    const int lane = t & 63, w = t >> 6;
    const int wr2 = (w >> 1) * 32, wc2 = (w & 1) * 64;
    const int g = lane >> 4, r16 = lane & 15;
    f32x4 acc[2][4] = {};

    // staging (BK=64): each gload_lds16 covers 8 rows x 64 cols (8 lanes/row)
    const int srow = lane >> 3;            // 0..7 within an 8-row group
    const int scol = (lane & 7) * 8;       // 0..56
    const u16* Ap = A + (size_t)(bm * 64 + w * 16 + srow) * K_ + scol;   // 2 instrs: +0, +8 rows
    const u16* Bp = B + (size_t)(bn * 128 + w * 32 + srow) * K_ + scol;  // 4 instrs: +0,+8,+16,+24
    const int aoff = w * 1024;   // 16 rows * 64
    const int boff = w * 2048;   // 32 rows * 64

    // prologue: stage tile 0 into buffer 0
    gload_lds16(Ap, &As[0][aoff]);
    gload_lds16(Ap + (size_t)8 * K_, &As[0][aoff + 512]);
    gload_lds16(Bp, &Bs[0][boff]);
    gload_lds16(Bp + (size_t)8 * K_, &Bs[0][boff + 512]);
    gload_lds16(Bp + (size_t)16 * K_, &Bs[0][boff + 1024]);
    gload_lds16(Bp + (size_t)24 * K_, &Bs[0][boff + 1536]);
    __syncthreads();

    int cur = 0;
    for (int kt = 0; kt < K_; kt += 64) {
        const int nxt = kt + 64;
        if (nxt < K_) {   // prefetch next K-step into the other buffer
            gload_lds16(Ap + nxt, &As[cur ^ 1][aoff]);
            gload_lds16(Ap + nxt + (size_t)8 * K_, &As[cur ^ 1][aoff + 512]);
            gload_lds16(Bp + nxt, &Bs[cur ^ 1][boff]);
            gload_lds16(Bp + nxt + (size_t)8 * K_, &Bs[cur ^ 1][boff + 512]);
            gload_lds16(Bp + nxt + (size_t)16 * K_, &Bs[cur ^ 1][boff + 1024]);
            gload_lds16(Bp + nxt + (size_t)24 * K_, &Bs[cur ^ 1][boff + 1536]);
        }
#pragma unroll
        for (int kk = 0; kk < 2; kk++) {
            bf16x8 af[2], bfr[4];
#pragma unroll
            for (int i = 0; i < 2; i++)
                af[i] = *(const bf16x8*)(&As[cur][(wr2 + i * 16 + r16) * 64 + kk * 32 + g * 8]);
#pragma unroll
            for (int j = 0; j < 4; j++)
                bfr[j] = *(const bf16x8*)(&Bs[cur][(wc2 + j * 16 + r16) * 64 + kk * 32 + g * 8]);
#pragma unroll
            for (int i = 0; i < 2; i++)
#pragma unroll
                for (int j = 0; j < 4; j++)
                    acc[i][j] = __builtin_amdgcn_mfma_f32_16x16x32_bf16(af[i], bfr[j], acc[i][j], 0, 0, 0);
        }
        __syncthreads();   // next-tile stage complete + all waves done reading cur
        cur ^= 1;
    }

    u16* qb_ = (u16*)Cv;
    u16* kb_ = qb_ + (size_t)2048 * 2048;
    u16* vt_ = kb_ + (size_t)512 * 2048;
    if (mode == 1) {
#pragma unroll
        for (int i = 0; i < 2; i++)
#pragma unroll
            for (int j = 0; j < 4; j++)
#pragma unroll
                for (int r = 0; r < 4; r++) {
                    int row = bm * 64 + wr2 + i * 16 + g * 4 + r;
                    int col = bn * 128 + wc2 + j * 16 + r16;
                    ((float*)Cv)[(size_t)row * ldc + col] = acc[i][j][r];
                }
    } else {
        const int cbase = bn * 128 + wc2;   // 64-aligned => wave span = one head
        if (cbase < 2560) {
            // q or k region: fused RoPE on fp32 accumulators (exact pre-round)
            const float scl = (cbase < 2048) ? 0.125f * 1.44269504f : 1.0f;
#pragma unroll
            for (int i = 0; i < 2; i++)
#pragma unroll
                for (int r = 0; r < 4; r++) {
                    int row = bm * 64 + wr2 + i * 16 + g * 4 + r;
#pragma unroll
                    for (int j = 0; j < 2; j++) {
                        int c0 = cbase + j * 16 + r16;
                        int iin = c0 & 63;                 // in-head dim, < 32
                        float x1 = acc[i][j][r], x2 = acc[i][j + 2][r];
                        float cA = cosp[row * 64 + iin],      sA = sinp[row * 64 + iin];
                        float cB = cosp[row * 64 + iin + 32], sB = sinp[row * 64 + iin + 32];
                        u16 o1 = f2bf((x1 * cA - x2 * sA) * scl);
                        u16 o2 = f2bf((x2 * cB + x1 * sB) * scl);
                        if (cbase < 2048) {
                            qb_[(size_t)row * 2048 + c0] = o1;
                            qb_[(size_t)row * 2048 + c0 + 32] = o2;
                        } else {
                            kb_[(size_t)row * 512 + (c0 - 2048)] = o1;
                            kb_[(size_t)row * 512 + (c0 - 2048 + 32)] = o2;
                        }
                    }
                }
        } else {
#pragma unroll
            for (int i = 0; i < 2; i++)
#pragma unroll
                for (int j = 0; j < 4; j++)
#pragma unroll
                    for (int r = 0; r < 4; r++) {
                        int row = bm * 64 + wr2 + i * 16 + g * 4 + r;
                        int col = cbase + j * 16 + r16;
                        vt_[(size_t)(col - 2560) * 2048 + row] = f2bf(acc[i][j][r]);
                    }
        }
    }
}

// ---------------- Flash attention (causal, GQA) ----------------
// R9 structure (proven 85.5 us): 1 wave/block, 32 q-rows/wave, KVBLK=128,
// barrier-free P LDS, K tile in registers with next-tile prefetch.
__global__ __launch_bounds__(64) void attn_kernel(const u16* __restrict__ q,
                                                  const u16* __restrict__ k,
                                                  const u16* __restrict__ vT,
                                                  u16* __restrict__ attn) {
    __shared__ u16 P[2][16][136];  // [frag][qrow][kcol]
    const int bid = blockIdx.x;
    const int h = bid & 31;
    const int qblk = 63 - (bid >> 5);   // heaviest blocks dispatch first
    const int lane = threadIdx.x & 63;
    const int g = lane >> 4, r16 = lane & 15;
    const int kvh = h >> 2;
    const int qrow0 = qblk * 32;

    bf16x8 qf[2][2];
#pragma unroll
    for (int fi = 0; fi < 2; fi++)
#pragma unroll
        for (int d = 0; d < 2; d++)
            qf[fi][d] = *(const bf16x8*)(q + (size_t)(qrow0 + fi * 16 + r16) * (NH * HD) + h * HD + d * 32 + g * 8);

    bf16x8 vone;
#pragma unroll
    for (int j = 0; j < 8; j++) vone[j] = (__bf16)1.0f;

    float m_run[2][4];
    f32x4 o[2][4] = {};
    f32x4 ol[2] = {};   // l ridden as an MFMA ones-column
#pragma unroll
    for (int fi = 0; fi < 2; fi++)
#pragma unroll
        for (int r = 0; r < 4; r++) m_run[fi][r] = -1e30f;

    const int last = (qrow0 >> 7) << 7;   // last 128-wide KV tile start

    // prologue: load K tile 0 (rows 0..127 always valid, S=2048)
    bf16x8 kA[4][2], kB[4][2];
#pragma unroll
    for (int s4 = 0; s4 < 4; s4++)
#pragma unroll
        for (int d = 0; d < 2; d++) {
            kA[s4][d] = *(const bf16x8*)(k + (size_t)(s4 * 16 + r16) * (NKV * HD) + kvh * HD + d * 32 + g * 8);
            kB[s4][d] = *(const bf16x8*)(k + (size_t)(64 + s4 * 16 + r16) * (NKV * HD) + kvh * HD + d * 32 + g * 8);
        }

    for (int kv = 0; kv <= last; kv += 128) {
        const bool diag = (kv == last);
        f32x4 sacc[2][8] = {};
        // ---- QK^T: 32 MFMA on registered K tile ----
#pragma unroll
        for (int s4 = 0; s4 < 4; s4++)
#pragma unroll
            for (int fi = 0; fi < 2; fi++)
#pragma unroll
                for (int d = 0; d < 2; d++)
                    sacc[fi][s4] = __builtin_amdgcn_mfma_f32_16x16x32_bf16(qf[fi][d], kA[s4][d], sacc[fi][s4], 0, 0, 0);
#pragma unroll
        for (int s4 = 0; s4 < 4; s4++)
#pragma unroll
            for (int fi = 0; fi < 2; fi++)
#pragma unroll
                for (int d = 0; d < 2; d++)
                    sacc[fi][4 + s4] = __builtin_amdgcn_mfma_f32_16x16x32_bf16(qf[fi][d], kB[s4][d], sacc[fi][4 + s4], 0, 0, 0);
        // ---- prefetch next K tile (latency hides under softmax+PV) ----
        if (kv + 128 <= last) {
            const int nk = kv + 128;
#pragma unroll
            for (int s4 = 0; s4 < 4; s4++)
#pragma unroll
                for (int d = 0; d < 2; d++) {
                    kA[s4][d] = *(const bf16x8*)(k + (size_t)(nk + s4 * 16 + r16) * (NKV * HD) + kvh * HD + d * 32 + g * 8);
                    kB[s4][d] = *(const bf16x8*)(k + (size_t)(nk + 64 + s4 * 16 + r16) * (NKV * HD) + kvh * HD + d * 32 + g * 8);
                }
        }
        // ---- V loads issued early: latency hides under softmax ----
        bf16x8 vf[4][4];
#pragma unroll
        for (int kq = 0; kq < 4; kq++)
#pragma unroll
            for (int dblk = 0; dblk < 4; dblk++)
                vf[kq][dblk] = *(const bf16x8*)(vT + (size_t)(kvh * HD + dblk * 16 + r16) * S_LEN + kv + kq * 32 + g * 8);
        // ---- causal mask (diagonal super-tile only) ----
        if (diag) {
#pragma unroll
            for (int fi = 0; fi < 2; fi++)
#pragma unroll
                for (int sub = 0; sub < 8; sub++)
#pragma unroll
                    for (int r = 0; r < 4; r++) {
                        int col = kv + sub * 16 + r16;
                        int row = qrow0 + fi * 16 + g * 4 + r;
                        if (col > row) sacc[fi][sub][r] = -1e30f;
                    }
        }
        // ---- softmax per fragment (max via shfl; sum via MFMA ones-column) ----
#pragma unroll
        for (int fi = 0; fi < 2; fi++) {
            float mt[4];
#pragma unroll
            for (int r = 0; r < 4; r++) {
                float a = fmaxf(fmaxf(sacc[fi][0][r], sacc[fi][1][r]), fmaxf(sacc[fi][2][r], sacc[fi][3][r]));
                float b = fmaxf(fmaxf(sacc[fi][4][r], sacc[fi][5][r]), fmaxf(sacc[fi][6][r], sacc[fi][7][r]));
                mt[r] = fmaxf(a, b);
            }
#pragma unroll
            for (int r = 0; r < 4; r++) {
                mt[r] = fmaxf(mt[r], __shfl_xor(mt[r], 1));
                mt[r] = fmaxf(mt[r], __shfl_xor(mt[r], 2));
                mt[r] = fmaxf(mt[r], __shfl_xor(mt[r], 4));
                mt[r] = fmaxf(mt[r], __shfl_xor(mt[r], 8));
            }
            // defer-max: skip rescale when running max doesn't grow (exact, deterministic)
            bool grow = (mt[0] > m_run[fi][0]) | (mt[1] > m_run[fi][1]) |
                        (mt[2] > m_run[fi][2]) | (mt[3] > m_run[fi][3]);
            if (__any(grow)) {
#pragma unroll
                for (int r = 0; r < 4; r++) {
                    float mn = fmaxf(m_run[fi][r], mt[r]);
                    float alpha = exp2f(m_run[fi][r] - mn);
                    m_run[fi][r] = mn;
                    ol[fi][r] *= alpha;
#pragma unroll
                    for (int dblk = 0; dblk < 4; dblk++) o[fi][dblk][r] *= alpha;
                }
            }
            // exp2 + P (C-layout) -> LDS with native packed cvt
#pragma unroll
            for (int sub = 0; sub < 8; sub++)
#pragma unroll
                for (int r = 0; r < 4; r++)
                    P[fi][g * 4 + r][sub * 16 + r16] = f2bf(exp2f(sacc[fi][sub][r] - m_run[fi][r]));
        }
        // ---- PV: 40 MFMA (4 dblk + 1 ones-column per kq per frag) ----
#pragma unroll
        for (int fi = 0; fi < 2; fi++)
#pragma unroll
            for (int kq = 0; kq < 4; kq++) {
                bf16x8 pf = *(const bf16x8*)(&P[fi][r16][kq * 32 + g * 8]);
                ol[fi] = __builtin_amdgcn_mfma_f32_16x16x32_bf16(pf, vone, ol[fi], 0, 0, 0);
#pragma unroll
                for (int dblk = 0; dblk < 4; dblk++)
                    o[fi][dblk] = __builtin_amdgcn_mfma_f32_16x16x32_bf16(pf, vf[kq][dblk], o[fi][dblk], 0, 0, 0);
            }
    }
#pragma unroll
    for (int fi = 0; fi < 2; fi++) {
        float inv[4];
#pragma unroll
        for (int r = 0; r < 4; r++) inv[r] = 1.0f / ol[fi][r];
#pragma unroll
        for (int dblk = 0; dblk < 4; dblk++)
#pragma unroll
            for (int r = 0; r < 4; r++) {
                float val = o[fi][dblk][r] * inv[r];
                attn[(size_t)(qrow0 + fi * 16 + g * 4 + r) * (NH * HD) + h * HD + dblk * 16 + r16] = f2bf(val);
            }
    }
}

extern "C" void kernel_launch(void* const* d_in, const int* in_sizes, int n_in,
                              void* d_out, int out_size, void* d_ws, size_t ws_size,
                              hipStream_t stream) {
    const float* hidden = (const float*)d_in[0];
    const float* Wq = (const float*)d_in[1];
    const float* Wk = (const float*)d_in[2];
    const float* Wv = (const float*)d_in[3];
    const float* Wo = (const float*)d_in[4];
    const float* cosp = (const float*)d_in[5];
    const float* sinp = (const float*)d_in[6];
    float* out = (float*)d_out;

    char* ws = (char*)d_ws;
    u16* hb   = (u16*)(ws);                        // 8 MB  [2048,2048]
    u16* wqkv = (u16*)(ws + ((size_t)8 << 20));    // 12 MB [3072,2048] (Wq;Wk;Wv)
    u16* wob  = (u16*)(ws + ((size_t)20 << 20));   // 8 MB  [2048,2048]
    u16* qbuf = (u16*)(ws + ((size_t)28 << 20));   // 8 MB  [2048,2048]  (kbuf, vT follow contiguously)
    u16* kbuf = qbuf + (size_t)2048 * 2048;        // 2 MB  [2048,512]
    u16* vT   = kbuf + (size_t)512 * 2048;         // 2 MB  [512,2048]
    u16* attn = (u16*)(ws + ((size_t)40 << 20));   // 8 MB  [2048,2048]

    // single fused fp32->bf16 conversion launch
    cvt_all<<<14336, 256, 0, stream>>>(hidden, Wq, Wk, Wv, Wo, hb, wqkv, wob);

    // fused QKV projection + RoPE epilogue: [2048,2048] x [3072,2048]^T, 64x128 tiles, BK=64
    gemm_bt<<<dim3(32, 24), 256, 0, stream>>>(hb, wqkv, qbuf, HID, 3, 0, cosp, sinp);

    // flash attention: R9 structure (1 wave/block, 32 q-rows, KVBLK=128, K-prefetch)
    attn_kernel<<<S_LEN / 32 * NH, 64, 0, stream>>>(qbuf, kbuf, vT, attn);

    // output projection -> fp32, 64x128 tiles, BK=64
    gemm_bt<<<dim3(32, 16), 256, 0, stream>>>(attn, wob, out, HID, 1, HID, nullptr, nullptr);

    (void)in_sizes; (void)n_in; (void)out_size; (void)ws_size;
}

// Round 12
// 181.070 us; speedup vs baseline: 1.0754x; 1.0077x over previous
//
#include <hip/hip_runtime.h>
#include <hip/hip_bf16.h>

typedef unsigned short u16;
typedef __bf16 bf16x8 __attribute__((ext_vector_type(8)));
typedef float f32x4 __attribute__((ext_vector_type(4)));

#define S_LEN 2048
#define HID 2048
#define NH 32
#define NKV 8
#define HD 64

// native RTNE f32->bf16 (single v_cvt op; compiler packs pairs)
__device__ inline u16 f2bf(float x) {
    __bf16 h = (__bf16)x;
    return __builtin_bit_cast(u16, h);
}
__device__ inline float bf2f(u16 u) {
    return __uint_as_float(((unsigned int)u) << 16);
}

__device__ inline void gload_lds16(const u16* g, u16* l) {
    __builtin_amdgcn_global_load_lds((const __attribute__((address_space(1))) unsigned int*)g,
                                     (__attribute__((address_space(3))) unsigned int*)l, 16, 0, 0);
}

// ---------------- fp32 -> bf16 convert, all 5 tensors in one launch ----------------
__global__ void cvt_all(const float* __restrict__ h, const float* __restrict__ wq,
                        const float* __restrict__ wk, const float* __restrict__ wv,
                        const float* __restrict__ wo,
                        u16* __restrict__ hb, u16* __restrict__ wqkv, u16* __restrict__ wob) {
    int i = blockIdx.x * blockDim.x + threadIdx.x;   // float4 index, total 3670016
    const float* src; u16* dst; int o;
    if (i < 1048576)      { src = h;  dst = hb;   o = i; }
    else if (i < 2097152) { src = wq; dst = wqkv; o = i - 1048576; }
    else if (i < 2359296) { src = wk; dst = wqkv + (size_t)2048 * 2048; o = i - 2097152; }
    else if (i < 2621440) { src = wv; dst = wqkv + (size_t)2560 * 2048; o = i - 2359296; }
    else                  { src = wo; dst = wob;  o = i - 2621440; }
    float4 v = ((const float4*)src)[o];
    ushort4 u;
    u.x = f2bf(v.x); u.y = f2bf(v.y); u.z = f2bf(v.z); u.w = f2bf(v.w);
    ((ushort4*)dst)[o] = u;
}

// ---------------- GEMM (R9-proven): 64x128 tile, BK=32, double-buffered ----------------
// mode 1: store fp32 row-major (ldc)
// mode 3: fused QKV epilogue with RoPE (wave col-span = 64 = one head)
__global__ __launch_bounds__(256) void gemm_bt(const u16* __restrict__ A,
                                               const u16* __restrict__ B,
                                               void* __restrict__ Cv,
                                               int K_, int mode, int ldc,
                                               const float* __restrict__ cosp,
                                               const float* __restrict__ sinp) {
    __shared__ u16 As[2][64 * 32];
    __shared__ u16 Bs[2][128 * 32];
    const int t = threadIdx.x;
    // XCD-aware bijective swizzle (nwg % 8 == 0 for both call sites)
    const int nwg = gridDim.x * gridDim.y;
    const int orig = blockIdx.y * gridDim.x + blockIdx.x;
    const int wgid = (orig & 7) * (nwg >> 3) + (orig >> 3);
    const int bm = wgid % gridDim.x, bn = wgid / gridDim.x;
    const int lane = t & 63, w = t >> 6;
    const int wr2 = (w >> 1) * 32, wc2 = (w & 1) * 64;
    const int g = lane >> 4, r16 = lane & 15;
    f32x4 acc[2][4] = {};

    // staging: A 64x32 (1 instr/wave: 16 rows), B 128x32 (2 instrs/wave: 32 rows)
    const int srowA = w * 16 + (lane >> 2);
    const int srowB = w * 32 + (lane >> 2);
    const int scol = (lane & 3) * 8;
    const u16* Ap = A + (size_t)(bm * 64 + srowA) * K_ + scol;
    const u16* Bp = B + (size_t)(bn * 128 + srowB) * K_ + scol;
    const int aoff = w * 512;    // 16 rows * 32
    const int boff = w * 1024;   // 32 rows * 32

    // prologue: stage tile 0 into buffer 0
    gload_lds16(Ap, &As[0][aoff]);
    gload_lds16(Bp, &Bs[0][boff]);
    gload_lds16(Bp + (size_t)16 * K_, &Bs[0][boff + 512]);
    __syncthreads();

    int cur = 0;
    for (int kt = 0; kt < K_; kt += 32) {
        const int nxt = kt + 32;
        if (nxt < K_) {   // prefetch next K-step into the other buffer
            gload_lds16(Ap + nxt, &As[cur ^ 1][aoff]);
            gload_lds16(Bp + nxt, &Bs[cur ^ 1][boff]);
            gload_lds16(Bp + nxt + (size_t)16 * K_, &Bs[cur ^ 1][boff + 512]);
        }
        bf16x8 af[2], bfr[4];
#pragma unroll
        for (int i = 0; i < 2; i++) af[i] = *(const bf16x8*)(&As[cur][(wr2 + i * 16 + r16) * 32 + g * 8]);
#pragma unroll
        for (int j = 0; j < 4; j++) bfr[j] = *(const bf16x8*)(&Bs[cur][(wc2 + j * 16 + r16) * 32 + g * 8]);
#pragma unroll
        for (int i = 0; i < 2; i++)
#pragma unroll
            for (int j = 0; j < 4; j++)
                acc[i][j] = __builtin_amdgcn_mfma_f32_16x16x32_bf16(af[i], bfr[j], acc[i][j], 0, 0, 0);
        __syncthreads();   // next-tile stage complete + all waves done reading cur
        cur ^= 1;
    }

    u16* qb_ = (u16*)Cv;
    u16* kb_ = qb_ + (size_t)2048 * 2048;
    u16* vt_ = kb_ + (size_t)512 * 2048;
    if (mode == 1) {
#pragma unroll
        for (int i = 0; i < 2; i++)
#pragma unroll
            for (int j = 0; j < 4; j++)
#pragma unroll
                for (int r = 0; r < 4; r++) {
                    int row = bm * 64 + wr2 + i * 16 + g * 4 + r;
                    int col = bn * 128 + wc2 + j * 16 + r16;
                    ((float*)Cv)[(size_t)row * ldc + col] = acc[i][j][r];
                }
    } else {
        const int cbase = bn * 128 + wc2;   // 64-aligned => wave span = one head
        if (cbase < 2560) {
            // q or k region: fused RoPE on fp32 accumulators (exact pre-round)
            const float scl = (cbase < 2048) ? 0.125f * 1.44269504f : 1.0f;
#pragma unroll
            for (int i = 0; i < 2; i++)
#pragma unroll
                for (int r = 0; r < 4; r++) {
                    int row = bm * 64 + wr2 + i * 16 + g * 4 + r;
#pragma unroll
                    for (int j = 0; j < 2; j++) {
                        int c0 = cbase + j * 16 + r16;
                        int iin = c0 & 63;                 // in-head dim, < 32
                        float x1 = acc[i][j][r], x2 = acc[i][j + 2][r];
                        float cA = cosp[row * 64 + iin],      sA = sinp[row * 64 + iin];
                        float cB = cosp[row * 64 + iin + 32], sB = sinp[row * 64 + iin + 32];
                        u16 o1 = f2bf((x1 * cA - x2 * sA) * scl);
                        u16 o2 = f2bf((x2 * cB + x1 * sB) * scl);
                        if (cbase < 2048) {
                            qb_[(size_t)row * 2048 + c0] = o1;
                            qb_[(size_t)row * 2048 + c0 + 32] = o2;
                        } else {
                            kb_[(size_t)row * 512 + (c0 - 2048)] = o1;
                            kb_[(size_t)row * 512 + (c0 - 2048 + 32)] = o2;
                        }
                    }
                }
        } else {
#pragma unroll
            for (int i = 0; i < 2; i++)
#pragma unroll
                for (int j = 0; j < 4; j++)
#pragma unroll
                    for (int r = 0; r < 4; r++) {
                        int row = bm * 64 + wr2 + i * 16 + g * 4 + r;
                        int col = cbase + j * 16 + r16;
                        vt_[(size_t)(col - 2560) * 2048 + row] = f2bf(acc[i][j][r]);
                    }
        }
    }
}

// ---------------- Flash attention (causal, GQA), software-pipelined ----------------
// 1 wave/block, 32 q-rows/wave, KVBLK=64, two S-register sets:
// QK(t+1) issued BEFORE softmax(t) so MFMA drains under the VALU phase.
// Static cur/nxt via macro (no runtime-indexed register arrays).

#define ATTN_TILE(SC, SN, T) do {                                                         \
    const int t_ = (T);                                                                   \
    const int kv_ = t_ * 64;                                                              \
    /* QK for tile t+1 into SN (kf holds K(t+1), loaded last iter) */                     \
    if (t_ + 1 < nt) {                                                                    \
        _Pragma("unroll") for (int s4 = 0; s4 < 4; s4++)                                  \
        _Pragma("unroll") for (int fi = 0; fi < 2; fi++) {                                \
            SN[fi][s4] = __builtin_amdgcn_mfma_f32_16x16x32_bf16(qf[fi][0], kf[s4][0], fzero, 0, 0, 0); \
            SN[fi][s4] = __builtin_amdgcn_mfma_f32_16x16x32_bf16(qf[fi][1], kf[s4][1], SN[fi][s4], 0, 0, 0); \
        }                                                                                 \
    }                                                                                     \
    /* issue K(t+2) loads (kf regs free after QK above read them) */                      \
    if (t_ + 2 < nt) {                                                                    \
        const int nk_ = (t_ + 2) * 64;                                                    \
        _Pragma("unroll") for (int s4 = 0; s4 < 4; s4++)                                  \
        _Pragma("unroll") for (int d = 0; d < 2; d++)                                     \
            kf[s4][d] = *(const bf16x8*)(k + (size_t)(nk_ + s4 * 16 + r16) * (NKV * HD) + kvh * HD + d * 32 + g * 8); \
    }                                                                                     \
    /* V(t) loads: latency hides under softmax */                                         \
    bf16x8 vf_[2][4];                                                                     \
    _Pragma("unroll") for (int kh = 0; kh < 2; kh++)                                      \
    _Pragma("unroll") for (int db = 0; db < 4; db++)                                      \
        vf_[kh][db] = *(const bf16x8*)(vT + (size_t)(kvh * HD + db * 16 + r16) * S_LEN + kv_ + kh * 32 + g * 8); \
    /* causal mask (diagonal tile only) */                                                \
    if (t_ == nt - 1) {                                                                   \
        _Pragma("unroll") for (int fi = 0; fi < 2; fi++)                                  \
        _Pragma("unroll") for (int sub = 0; sub < 4; sub++)                               \
        _Pragma("unroll") for (int r = 0; r < 4; r++) {                                   \
            int col_ = kv_ + sub * 16 + r16;                                              \
            int row_ = qrow0 + fi * 16 + g * 4 + r;                                       \
            if (col_ > row_) SC[fi][sub][r] = -1e30f;                                     \
        }                                                                                 \
    }                                                                                     \
    /* softmax on SC (computed last iter -> no MFMA wait) */                              \
    _Pragma("unroll") for (int fi = 0; fi < 2; fi++) {                                    \
        float mt[4];                                                                      \
        _Pragma("unroll") for (int r = 0; r < 4; r++)                                     \
            mt[r] = fmaxf(fmaxf(SC[fi][0][r], SC[fi][1][r]), fmaxf(SC[fi][2][r], SC[fi][3][r])); \
        _Pragma("unroll") for (int r = 0; r < 4; r++) {                                   \
            mt[r] = fmaxf(mt[r], __shfl_xor(mt[r], 1));                                   \
            mt[r] = fmaxf(mt[r], __shfl_xor(mt[r], 2));                                   \
            mt[r] = fmaxf(mt[r], __shfl_xor(mt[r], 4));                                   \
            mt[r] = fmaxf(mt[r], __shfl_xor(mt[r], 8));                                   \
        }                                                                                 \
        bool grow = (mt[0] > m_run[fi][0]) | (mt[1] > m_run[fi][1]) |                     \
                    (mt[2] > m_run[fi][2]) | (mt[3] > m_run[fi][3]);                      \
        if (__any(grow)) {                                                                \
            _Pragma("unroll") for (int r = 0; r < 4; r++) {                               \
                float mn = fmaxf(m_run[fi][r], mt[r]);                                    \
                float alpha = exp2f(m_run[fi][r] - mn);                                   \
                m_run[fi][r] = mn;                                                        \
                ol[fi][r] *= alpha;                                                       \
                _Pragma("unroll") for (int db = 0; db < 4; db++) o[fi][db][r] *= alpha;   \
            }                                                                             \
        }                                                                                 \
        _Pragma("unroll") for (int sub = 0; sub < 4; sub++)                               \
        _Pragma("unroll") for (int r = 0; r < 4; r++)                                     \
            P[fi][g * 4 + r][sub * 16 + r16] = f2bf(exp2f(SC[fi][sub][r] - m_run[fi][r])); \
    }                                                                                     \
    /* PV: 20 MFMA (4 dblk + ones-column per khalf per frag) */                           \
    _Pragma("unroll") for (int fi = 0; fi < 2; fi++)                                      \
    _Pragma("unroll") for (int kh = 0; kh < 2; kh++) {                                    \
        bf16x8 pf = *(const bf16x8*)(&P[fi][r16][kh * 32 + g * 8]);                       \
        ol[fi] = __builtin_amdgcn_mfma_f32_16x16x32_bf16(pf, vone, ol[fi], 0, 0, 0);      \
        _Pragma("unroll") for (int db = 0; db < 4; db++)                                  \
            o[fi][db] = __builtin_amdgcn_mfma_f32_16x16x32_bf16(pf, vf_[kh][db], o[fi][db], 0, 0, 0); \
    }                                                                                     \
} while (0)

__global__ __launch_bounds__(64) void attn_kernel(const u16* __restrict__ q,
                                                  const u16* __restrict__ k,
                                                  const u16* __restrict__ vT,
                                                  u16* __restrict__ attn) {
    __shared__ u16 P[2][16][72];   // [frag][qrow][kcol], 144B row stride
    const int bid = blockIdx.x;
    const int h = bid & 31;
    const int qblk = 63 - (bid >> 5);   // heaviest blocks dispatch first
    const int lane = threadIdx.x & 63;
    const int g = lane >> 4, r16 = lane & 15;
    const int kvh = h >> 2;
    const int qrow0 = qblk * 32;
    const int nt = (qblk >> 1) + 1;     // number of 64-col KV tiles

    const f32x4 fzero = {0.f, 0.f, 0.f, 0.f};

    bf16x8 qf[2][2];
#pragma unroll
    for (int fi = 0; fi < 2; fi++)
#pragma unroll
        for (int d = 0; d < 2; d++)
            qf[fi][d] = *(const bf16x8*)(q + (size_t)(qrow0 + fi * 16 + r16) * (NH * HD) + h * HD + d * 32 + g * 8);

    bf16x8 vone;
#pragma unroll
    for (int j = 0; j < 8; j++) vone[j] = (__bf16)1.0f;

    float m_run[2][4];
    f32x4 o[2][4] = {};
    f32x4 ol[2] = {};   // l ridden as an MFMA ones-column
#pragma unroll
    for (int fi = 0; fi < 2; fi++)
#pragma unroll
        for (int r = 0; r < 4; r++) m_run[fi][r] = -1e30f;

    // ---- prologue: K(0) -> QK(0) -> sA; then load K(1) ----
    bf16x8 kf[4][2];
#pragma unroll
    for (int s4 = 0; s4 < 4; s4++)
#pragma unroll
        for (int d = 0; d < 2; d++)
            kf[s4][d] = *(const bf16x8*)(k + (size_t)(s4 * 16 + r16) * (NKV * HD) + kvh * HD + d * 32 + g * 8);

    f32x4 sA[2][4], sB[2][4];
#pragma unroll
    for (int s4 = 0; s4 < 4; s4++)
#pragma unroll
        for (int fi = 0; fi < 2; fi++) {
            sA[fi][s4] = __builtin_amdgcn_mfma_f32_16x16x32_bf16(qf[fi][0], kf[s4][0], fzero, 0, 0, 0);
            sA[fi][s4] = __builtin_amdgcn_mfma_f32_16x16x32_bf16(qf[fi][1], kf[s4][1], sA[fi][s4], 0, 0, 0);
        }
    if (nt > 1) {
#pragma unroll
        for (int s4 = 0; s4 < 4; s4++)
#pragma unroll
            for (int d = 0; d < 2; d++)
                kf[s4][d] = *(const bf16x8*)(k + (size_t)(64 + s4 * 16 + r16) * (NKV * HD) + kvh * HD + d * 32 + g * 8);
    }

    // ---- pipelined main loop (static A/B swap) ----
    int t = 0;
    for (;;) {
        ATTN_TILE(sA, sB, t);
        if (++t == nt) break;
        ATTN_TILE(sB, sA, t);
        if (++t == nt) break;
    }

    // ---- epilogue ----
#pragma unroll
    for (int fi = 0; fi < 2; fi++) {
        float inv[4];
#pragma unroll
        for (int r = 0; r < 4; r++) inv[r] = 1.0f / ol[fi][r];
#pragma unroll
        for (int db = 0; db < 4; db++)
#pragma unroll
            for (int r = 0; r < 4; r++) {
                float val = o[fi][db][r] * inv[r];
                attn[(size_t)(qrow0 + fi * 16 + g * 4 + r) * (NH * HD) + h * HD + db * 16 + r16] = f2bf(val);
            }
    }
}

extern "C" void kernel_launch(void* const* d_in, const int* in_sizes, int n_in,
                              void* d_out, int out_size, void* d_ws, size_t ws_size,
                              hipStream_t stream) {
    const float* hidden = (const float*)d_in[0];
    const float* Wq = (const float*)d_in[1];
    const float* Wk = (const float*)d_in[2];
    const float* Wv = (const float*)d_in[3];
    const float* Wo = (const float*)d_in[4];
    const float* cosp = (const float*)d_in[5];
    const float* sinp = (const float*)d_in[6];
    float* out = (float*)d_out;

    char* ws = (char*)d_ws;
    u16* hb   = (u16*)(ws);                        // 8 MB  [2048,2048]
    u16* wqkv = (u16*)(ws + ((size_t)8 << 20));    // 12 MB [3072,2048] (Wq;Wk;Wv)
    u16* wob  = (u16*)(ws + ((size_t)20 << 20));   // 8 MB  [2048,2048]
    u16* qbuf = (u16*)(ws + ((size_t)28 << 20));   // 8 MB  [2048,2048]  (kbuf, vT follow contiguously)
    u16* kbuf = qbuf + (size_t)2048 * 2048;        // 2 MB  [2048,512]
    u16* vT   = kbuf + (size_t)512 * 2048;         // 2 MB  [512,2048]
    u16* attn = (u16*)(ws + ((size_t)40 << 20));   // 8 MB  [2048,2048]

    // single fused fp32->bf16 conversion launch
    cvt_all<<<14336, 256, 0, stream>>>(hidden, Wq, Wk, Wv, Wo, hb, wqkv, wob);

    // fused QKV projection + RoPE epilogue: [2048,2048] x [3072,2048]^T, 64x128 tiles, BK=32
    gemm_bt<<<dim3(32, 24), 256, 0, stream>>>(hb, wqkv, qbuf, HID, 3, 0, cosp, sinp);

    // flash attention: pipelined (QK(t+1) under softmax(t)), KVBLK=64
    attn_kernel<<<S_LEN / 32 * NH, 64, 0, stream>>>(qbuf, kbuf, vT, attn);

    // output projection -> fp32, 64x128 tiles, BK=32
    gemm_bt<<<dim3(32, 16), 256, 0, stream>>>(attn, wob, out, HID, 1, HID, nullptr, nullptr);

    (void)in_sizes; (void)n_in; (void)out_size; (void)ws_size;
}

// Round 13
// 177.545 us; speedup vs baseline: 1.0967x; 1.0199x over previous
//
#include <hip/hip_runtime.h>
#include <hip/hip_bf16.h>

typedef unsigned short u16;
typedef __bf16 bf16x8 __attribute__((ext_vector_type(8)));
typedef float f32x4 __attribute__((ext_vector_type(4)));

#define S_LEN 2048
#define HID 2048
#define NH 32
#define NKV 8
#define HD 64

// native RTNE f32->bf16 (single v_cvt op; compiler packs pairs)
__device__ inline u16 f2bf(float x) {
    __bf16 h = (__bf16)x;
    return __builtin_bit_cast(u16, h);
}
__device__ inline float bf2f(u16 u) {
    return __uint_as_float(((unsigned int)u) << 16);
}

__device__ inline void gload_lds16(const u16* g, u16* l) {
    __builtin_amdgcn_global_load_lds((const __attribute__((address_space(1))) unsigned int*)g,
                                     (__attribute__((address_space(3))) unsigned int*)l, 16, 0, 0);
}

// ---------------- fp32 -> bf16 convert, all 5 tensors in one launch ----------------
__global__ void cvt_all(const float* __restrict__ h, const float* __restrict__ wq,
                        const float* __restrict__ wk, const float* __restrict__ wv,
                        const float* __restrict__ wo,
                        u16* __restrict__ hb, u16* __restrict__ wqkv, u16* __restrict__ wob) {
    int i = blockIdx.x * blockDim.x + threadIdx.x;   // float4 index, total 3670016
    const float* src; u16* dst; int o;
    if (i < 1048576)      { src = h;  dst = hb;   o = i; }
    else if (i < 2097152) { src = wq; dst = wqkv; o = i - 1048576; }
    else if (i < 2359296) { src = wk; dst = wqkv + (size_t)2048 * 2048; o = i - 2097152; }
    else if (i < 2621440) { src = wv; dst = wqkv + (size_t)2560 * 2048; o = i - 2359296; }
    else                  { src = wo; dst = wob;  o = i - 2621440; }
    float4 v = ((const float4*)src)[o];
    ushort4 u;
    u.x = f2bf(v.x); u.y = f2bf(v.y); u.z = f2bf(v.z); u.w = f2bf(v.w);
    ((ushort4*)dst)[o] = u;
}

// ---------------- GEMM (R9-proven): 64x128 tile, BK=32, double-buffered ----------------
// mode 1: store fp32 row-major (ldc)
// mode 3: fused QKV epilogue with RoPE (wave col-span = 64 = one head)
__global__ __launch_bounds__(256) void gemm_bt(const u16* __restrict__ A,
                                               const u16* __restrict__ B,
                                               void* __restrict__ Cv,
                                               int K_, int mode, int ldc,
                                               const float* __restrict__ cosp,
                                               const float* __restrict__ sinp) {
    __shared__ u16 As[2][64 * 32];
    __shared__ u16 Bs[2][128 * 32];
    const int t = threadIdx.x;
    // XCD-aware bijective swizzle (nwg % 8 == 0 for both call sites)
    const int nwg = gridDim.x * gridDim.y;
    const int orig = blockIdx.y * gridDim.x + blockIdx.x;
    const int wgid = (orig & 7) * (nwg >> 3) + (orig >> 3);
    const int bm = wgid % gridDim.x, bn = wgid / gridDim.x;
    const int lane = t & 63, w = t >> 6;
    const int wr2 = (w >> 1) * 32, wc2 = (w & 1) * 64;
    const int g = lane >> 4, r16 = lane & 15;
    f32x4 acc[2][4] = {};

    // staging: A 64x32 (1 instr/wave: 16 rows), B 128x32 (2 instrs/wave: 32 rows)
    const int srowA = w * 16 + (lane >> 2);
    const int srowB = w * 32 + (lane >> 2);
    const int scol = (lane & 3) * 8;
    const u16* Ap = A + (size_t)(bm * 64 + srowA) * K_ + scol;
    const u16* Bp = B + (size_t)(bn * 128 + srowB) * K_ + scol;
    const int aoff = w * 512;    // 16 rows * 32
    const int boff = w * 1024;   // 32 rows * 32

    // prologue: stage tile 0 into buffer 0
    gload_lds16(Ap, &As[0][aoff]);
    gload_lds16(Bp, &Bs[0][boff]);
    gload_lds16(Bp + (size_t)16 * K_, &Bs[0][boff + 512]);
    __syncthreads();

    int cur = 0;
    for (int kt = 0; kt < K_; kt += 32) {
        const int nxt = kt + 32;
        if (nxt < K_) {   // prefetch next K-step into the other buffer
            gload_lds16(Ap + nxt, &As[cur ^ 1][aoff]);
            gload_lds16(Bp + nxt, &Bs[cur ^ 1][boff]);
            gload_lds16(Bp + nxt + (size_t)16 * K_, &Bs[cur ^ 1][boff + 512]);
        }
        bf16x8 af[2], bfr[4];
#pragma unroll
        for (int i = 0; i < 2; i++) af[i] = *(const bf16x8*)(&As[cur][(wr2 + i * 16 + r16) * 32 + g * 8]);
#pragma unroll
        for (int j = 0; j < 4; j++) bfr[j] = *(const bf16x8*)(&Bs[cur][(wc2 + j * 16 + r16) * 32 + g * 8]);
#pragma unroll
        for (int i = 0; i < 2; i++)
#pragma unroll
            for (int j = 0; j < 4; j++)
                acc[i][j] = __builtin_amdgcn_mfma_f32_16x16x32_bf16(af[i], bfr[j], acc[i][j], 0, 0, 0);
        __syncthreads();   // next-tile stage complete + all waves done reading cur
        cur ^= 1;
    }

    u16* qb_ = (u16*)Cv;
    u16* kb_ = qb_ + (size_t)2048 * 2048;
    u16* vt_ = kb_ + (size_t)512 * 2048;
    if (mode == 1) {
#pragma unroll
        for (int i = 0; i < 2; i++)
#pragma unroll
            for (int j = 0; j < 4; j++)
#pragma unroll
                for (int r = 0; r < 4; r++) {
                    int row = bm * 64 + wr2 + i * 16 + g * 4 + r;
                    int col = bn * 128 + wc2 + j * 16 + r16;
                    ((float*)Cv)[(size_t)row * ldc + col] = acc[i][j][r];
                }
    } else {
        const int cbase = bn * 128 + wc2;   // 64-aligned => wave span = one head
        if (cbase < 2560) {
            // q or k region: fused RoPE on fp32 accumulators (exact pre-round)
            const float scl = (cbase < 2048) ? 0.125f * 1.44269504f : 1.0f;
#pragma unroll
            for (int i = 0; i < 2; i++)
#pragma unroll
                for (int r = 0; r < 4; r++) {
                    int row = bm * 64 + wr2 + i * 16 + g * 4 + r;
#pragma unroll
                    for (int j = 0; j < 2; j++) {
                        int c0 = cbase + j * 16 + r16;
                        int iin = c0 & 63;                 // in-head dim, < 32
                        float x1 = acc[i][j][r], x2 = acc[i][j + 2][r];
                        float cA = cosp[row * 64 + iin],      sA = sinp[row * 64 + iin];
                        float cB = cosp[row * 64 + iin + 32], sB = sinp[row * 64 + iin + 32];
                        u16 o1 = f2bf((x1 * cA - x2 * sA) * scl);
                        u16 o2 = f2bf((x2 * cB + x1 * sB) * scl);
                        if (cbase < 2048) {
                            qb_[(size_t)row * 2048 + c0] = o1;
                            qb_[(size_t)row * 2048 + c0 + 32] = o2;
                        } else {
                            kb_[(size_t)row * 512 + (c0 - 2048)] = o1;
                            kb_[(size_t)row * 512 + (c0 - 2048 + 32)] = o2;
                        }
                    }
                }
        } else {
#pragma unroll
            for (int i = 0; i < 2; i++)
#pragma unroll
                for (int j = 0; j < 4; j++)
#pragma unroll
                    for (int r = 0; r < 4; r++) {
                        int row = bm * 64 + wr2 + i * 16 + g * 4 + r;
                        int col = cbase + j * 16 + r16;
                        vt_[(size_t)(col - 2560) * 2048 + row] = f2bf(acc[i][j][r]);
                    }
        }
    }
}

// ---------------- Flash attention (causal, GQA), paired units ----------------
// R9 per-unit structure EXACTLY (1 wave, 32 q-rows, KVBLK=128, in-reg K with
// next-tile prefetch, ones-column l, defer-max). Each wave runs TWO full units
// (h, 63-p) then (h, p): per-wave tiles = 16..17, uniform -> no straggler tail.
__global__ __launch_bounds__(64) void attn_kernel(const u16* __restrict__ q,
                                                  const u16* __restrict__ k,
                                                  const u16* __restrict__ vT,
                                                  u16* __restrict__ attn) {
    __shared__ u16 P[2][16][136];  // [frag][qrow][kcol]
    const int bid = blockIdx.x;
    const int h = bid & 31;
    const int p = bid >> 5;            // 0..31 pair index
    const int lane = threadIdx.x & 63;
    const int g = lane >> 4, r16 = lane & 15;
    const int kvh = h >> 2;

    bf16x8 vone;
#pragma unroll
    for (int j = 0; j < 8; j++) vone[j] = (__bf16)1.0f;

    for (int u = 0; u < 2; u++) {
        const int qblk = u ? p : 63 - p;   // heavy unit first
        const int qrow0 = qblk * 32;

        bf16x8 qf[2][2];
#pragma unroll
        for (int fi = 0; fi < 2; fi++)
#pragma unroll
            for (int d = 0; d < 2; d++)
                qf[fi][d] = *(const bf16x8*)(q + (size_t)(qrow0 + fi * 16 + r16) * (NH * HD) + h * HD + d * 32 + g * 8);

        float m_run[2][4];
        f32x4 o[2][4] = {};
        f32x4 ol[2] = {};   // l ridden as an MFMA ones-column
#pragma unroll
        for (int fi = 0; fi < 2; fi++)
#pragma unroll
            for (int r = 0; r < 4; r++) m_run[fi][r] = -1e30f;

        const int last = (qrow0 >> 7) << 7;   // last 128-wide KV tile start

        // prologue: load K tile 0
        bf16x8 kA[4][2], kB[4][2];
#pragma unroll
        for (int s4 = 0; s4 < 4; s4++)
#pragma unroll
            for (int d = 0; d < 2; d++) {
                kA[s4][d] = *(const bf16x8*)(k + (size_t)(s4 * 16 + r16) * (NKV * HD) + kvh * HD + d * 32 + g * 8);
                kB[s4][d] = *(const bf16x8*)(k + (size_t)(64 + s4 * 16 + r16) * (NKV * HD) + kvh * HD + d * 32 + g * 8);
            }

        for (int kv = 0; kv <= last; kv += 128) {
            const bool diag = (kv == last);
            f32x4 sacc[2][8] = {};
            // ---- QK^T: 32 MFMA on registered K tile ----
#pragma unroll
            for (int s4 = 0; s4 < 4; s4++)
#pragma unroll
                for (int fi = 0; fi < 2; fi++)
#pragma unroll
                    for (int d = 0; d < 2; d++)
                        sacc[fi][s4] = __builtin_amdgcn_mfma_f32_16x16x32_bf16(qf[fi][d], kA[s4][d], sacc[fi][s4], 0, 0, 0);
#pragma unroll
            for (int s4 = 0; s4 < 4; s4++)
#pragma unroll
                for (int fi = 0; fi < 2; fi++)
#pragma unroll
                    for (int d = 0; d < 2; d++)
                        sacc[fi][4 + s4] = __builtin_amdgcn_mfma_f32_16x16x32_bf16(qf[fi][d], kB[s4][d], sacc[fi][4 + s4], 0, 0, 0);
            // ---- prefetch next K tile (latency hides under softmax+PV) ----
            if (kv + 128 <= last) {
                const int nk = kv + 128;
#pragma unroll
                for (int s4 = 0; s4 < 4; s4++)
#pragma unroll
                    for (int d = 0; d < 2; d++) {
                        kA[s4][d] = *(const bf16x8*)(k + (size_t)(nk + s4 * 16 + r16) * (NKV * HD) + kvh * HD + d * 32 + g * 8);
                        kB[s4][d] = *(const bf16x8*)(k + (size_t)(nk + 64 + s4 * 16 + r16) * (NKV * HD) + kvh * HD + d * 32 + g * 8);
                    }
            }
            // ---- V loads issued early: latency hides under softmax ----
            bf16x8 vf[4][4];
#pragma unroll
            for (int kq = 0; kq < 4; kq++)
#pragma unroll
                for (int dblk = 0; dblk < 4; dblk++)
                    vf[kq][dblk] = *(const bf16x8*)(vT + (size_t)(kvh * HD + dblk * 16 + r16) * S_LEN + kv + kq * 32 + g * 8);
            // ---- causal mask (diagonal super-tile only) ----
            if (diag) {
#pragma unroll
                for (int fi = 0; fi < 2; fi++)
#pragma unroll
                    for (int sub = 0; sub < 8; sub++)
#pragma unroll
                        for (int r = 0; r < 4; r++) {
                            int col = kv + sub * 16 + r16;
                            int row = qrow0 + fi * 16 + g * 4 + r;
                            if (col > row) sacc[fi][sub][r] = -1e30f;
                        }
            }
            // ---- softmax per fragment (max via shfl; sum via MFMA ones-column) ----
#pragma unroll
            for (int fi = 0; fi < 2; fi++) {
                float mt[4];
#pragma unroll
                for (int r = 0; r < 4; r++) {
                    float a = fmaxf(fmaxf(sacc[fi][0][r], sacc[fi][1][r]), fmaxf(sacc[fi][2][r], sacc[fi][3][r]));
                    float b = fmaxf(fmaxf(sacc[fi][4][r], sacc[fi][5][r]), fmaxf(sacc[fi][6][r], sacc[fi][7][r]));
                    mt[r] = fmaxf(a, b);
                }
#pragma unroll
                for (int r = 0; r < 4; r++) {
                    mt[r] = fmaxf(mt[r], __shfl_xor(mt[r], 1));
                    mt[r] = fmaxf(mt[r], __shfl_xor(mt[r], 2));
                    mt[r] = fmaxf(mt[r], __shfl_xor(mt[r], 4));
                    mt[r] = fmaxf(mt[r], __shfl_xor(mt[r], 8));
                }
                // defer-max: skip rescale when running max doesn't grow
                bool grow = (mt[0] > m_run[fi][0]) | (mt[1] > m_run[fi][1]) |
                            (mt[2] > m_run[fi][2]) | (mt[3] > m_run[fi][3]);
                if (__any(grow)) {
#pragma unroll
                    for (int r = 0; r < 4; r++) {
                        float mn = fmaxf(m_run[fi][r], mt[r]);
                        float alpha = exp2f(m_run[fi][r] - mn);
                        m_run[fi][r] = mn;
                        ol[fi][r] *= alpha;
#pragma unroll
                        for (int dblk = 0; dblk < 4; dblk++) o[fi][dblk][r] *= alpha;
                    }
                }
                // exp2 + P (C-layout) -> LDS with native packed cvt
#pragma unroll
                for (int sub = 0; sub < 8; sub++)
#pragma unroll
                    for (int r = 0; r < 4; r++)
                        P[fi][g * 4 + r][sub * 16 + r16] = f2bf(exp2f(sacc[fi][sub][r] - m_run[fi][r]));
            }
            // ---- PV: 40 MFMA (4 dblk + 1 ones-column per kq per frag) ----
#pragma unroll
            for (int fi = 0; fi < 2; fi++)
#pragma unroll
                for (int kq = 0; kq < 4; kq++) {
                    bf16x8 pf = *(const bf16x8*)(&P[fi][r16][kq * 32 + g * 8]);
                    ol[fi] = __builtin_amdgcn_mfma_f32_16x16x32_bf16(pf, vone, ol[fi], 0, 0, 0);
#pragma unroll
                    for (int dblk = 0; dblk < 4; dblk++)
                        o[fi][dblk] = __builtin_amdgcn_mfma_f32_16x16x32_bf16(pf, vf[kq][dblk], o[fi][dblk], 0, 0, 0);
                }
        }
        // ---- unit epilogue ----
#pragma unroll
        for (int fi = 0; fi < 2; fi++) {
            float inv[4];
#pragma unroll
            for (int r = 0; r < 4; r++) inv[r] = 1.0f / ol[fi][r];
#pragma unroll
            for (int dblk = 0; dblk < 4; dblk++)
#pragma unroll
                for (int r = 0; r < 4; r++) {
                    float val = o[fi][dblk][r] * inv[r];
                    attn[(size_t)(qrow0 + fi * 16 + g * 4 + r) * (NH * HD) + h * HD + dblk * 16 + r16] = f2bf(val);
                }
        }
    }
}

extern "C" void kernel_launch(void* const* d_in, const int* in_sizes, int n_in,
                              void* d_out, int out_size, void* d_ws, size_t ws_size,
                              hipStream_t stream) {
    const float* hidden = (const float*)d_in[0];
    const float* Wq = (const float*)d_in[1];
    const float* Wk = (const float*)d_in[2];
    const float* Wv = (const float*)d_in[3];
    const float* Wo = (const float*)d_in[4];
    const float* cosp = (const float*)d_in[5];
    const float* sinp = (const float*)d_in[6];
    float* out = (float*)d_out;

    char* ws = (char*)d_ws;
    u16* hb   = (u16*)(ws);                        // 8 MB  [2048,2048]
    u16* wqkv = (u16*)(ws + ((size_t)8 << 20));    // 12 MB [3072,2048] (Wq;Wk;Wv)
    u16* wob  = (u16*)(ws + ((size_t)20 << 20));   // 8 MB  [2048,2048]
    u16* qbuf = (u16*)(ws + ((size_t)28 << 20));   // 8 MB  [2048,2048]  (kbuf, vT follow contiguously)
    u16* kbuf = qbuf + (size_t)2048 * 2048;        // 2 MB  [2048,512]
    u16* vT   = kbuf + (size_t)512 * 2048;         // 2 MB  [512,2048]
    u16* attn = (u16*)(ws + ((size_t)40 << 20));   // 8 MB  [2048,2048]

    // single fused fp32->bf16 conversion launch
    cvt_all<<<14336, 256, 0, stream>>>(hidden, Wq, Wk, Wv, Wo, hb, wqkv, wob);

    // fused QKV projection + RoPE epilogue: [2048,2048] x [3072,2048]^T, 64x128 tiles, BK=32
    gemm_bt<<<dim3(32, 24), 256, 0, stream>>>(hb, wqkv, qbuf, HID, 3, 0, cosp, sinp);

    // flash attention: paired units (qblk 63-p then p), uniform 16-17 tiles/wave
    attn_kernel<<<S_LEN / 64 * NH, 64, 0, stream>>>(qbuf, kbuf, vT, attn);

    // output projection -> fp32, 64x128 tiles, BK=32
    gemm_bt<<<dim3(32, 16), 256, 0, stream>>>(attn, wob, out, HID, 1, HID, nullptr, nullptr);

    (void)in_sizes; (void)n_in; (void)out_size; (void)ws_size;
}